// Round 6
// baseline (206.011 us; speedup 1.0000x reference)
//
#include <hip/hip_runtime.h>

// x [B=16, N=1024, F=256] fp32.  Algebra (alpha folded away):
//   WfA = pack(Wa^T @ Wb), WfC = pack(Wr@Wu), bc = Wr@bu   (prep; MFMA-fragment-packed)
//   ab  = x @ Wab^T   (proj)               U2 = x @ Wcb^T + bc
//   d[m] = x[m]·ab[m] (diag term)
//   G[b][j][f] = sum_i U2[b,i,j] * ab[b,i,f]   (split-K fp32 halves)
//   out[m,j] = (x[m,:]·G[b][j,:] - d[m]*U2[m,j]) / N + x[m,j]
// Round-6: byte-cut per the fixed-rate latency model (R3-R5 invariant ~1.4TB/s):
//   - final fuses U2 inline (x@WfC^T+bc, weights L2-hot) -> U2 buffer deleted
//     (-8MB write, -8MB read); XCD-swizzled grid (batch-co-located).
//   - m2: 64x64 tiles, split-K(2), XCD swizzle puts each batch's 32 blocks on
//     one XCD -> operands L2-resident, FETCH ~90->~20MB.
//   - proj: R5 structure minus U2-natural epilogue.

typedef __bf16 bf16;
typedef float floatx4 __attribute__((ext_vector_type(4)));
typedef bf16 bf16x8 __attribute__((ext_vector_type(8)));

constexpr int FD = 256;
constexpr int NB = 16;
constexpr int NN = 1024;
constexpr int RR = NB * NN;       // 16384
constexpr int GH = NB * FD * FD;  // one split-K half of G (fp32 elems)

__device__ __forceinline__ bf16x8 cvt8(float4 a, float4 b) {
    bf16x8 o = { (bf16)a.x, (bf16)a.y, (bf16)a.z, (bf16)a.w,
                 (bf16)b.x, (bf16)b.y, (bf16)b.z, (bf16)b.w };
    return o;
}

// fragment-packed index for a [256][256] B-operand consumed as 16-col frags:
// chunk (f16,g32) is 1KB; lane = ((g>>3)&3)*16 + (f&15); elem g&7.
__device__ __forceinline__ int pk(int f, int g) {
    return ((f >> 4) * 8 + (g >> 5)) * 512 + (((g >> 3) & 3) * 16 + (f & 15)) * 8 + (g & 7);
}

// ---------------- K1: prep ----------------
__global__ __launch_bounds__(256)
void prep(const float* __restrict__ Wa, const float* __restrict__ Wb,
          const float* __restrict__ Wu, const float* __restrict__ bu,
          const float* __restrict__ Wr,
          bf16* __restrict__ WfC, bf16* __restrict__ WfA, float* __restrict__ bc)
{
    const int blk = blockIdx.x, tid = threadIdx.x;
    if (blk < 256) {  // Wcb[j][f] = sum_g Wr[j][g]*Wu[g][f]; one j per block
        const int j = blk;
        float acc = 0.0f;
        for (int g = 0; g < FD; g += 4) {
            float4 wr = *(const float4*)&Wr[j * FD + g];
            acc += wr.x * Wu[g * FD + tid] + wr.y * Wu[(g + 1) * FD + tid]
                 + wr.z * Wu[(g + 2) * FD + tid] + wr.w * Wu[(g + 3) * FD + tid];
        }
        WfC[pk(j, tid)] = (bf16)acc;
    } else if (blk == 256) {  // bc[j] = Wr[j,:].bu
        float s = 0.0f;
        for (int g = 0; g < FD; g++) s += Wr[tid * FD + g] * bu[g];
        bc[tid] = s;
    } else {  // Wab[f][g] = sum_k Wa[k][f]*Wb[k][g]; one f per block
        const int f = blk - 257;
        float acc = 0.0f;
        for (int k = 0; k < FD; k += 4) {
            acc += Wa[k * FD + f] * Wb[k * FD + tid]
                 + Wa[(k + 1) * FD + f] * Wb[(k + 1) * FD + tid]
                 + Wa[(k + 2) * FD + f] * Wb[(k + 2) * FD + tid]
                 + Wa[(k + 3) * FD + f] * Wb[(k + 3) * FD + tid];
        }
        WfA[pk(f, tid)] = (bf16)acc;
    }
}

// ---------------- K2: proj (16-row strip x 256 cols; x read once; packed B) ----------------
// block = 256 thr = 4 waves; wave w owns col-quarter [w*64, w*64+64). grid 1024.
__global__ __launch_bounds__(256, 4)
void proj(const float* __restrict__ x,
          const bf16* __restrict__ WfA, const bf16* __restrict__ WfC,
          bf16* __restrict__ abT, bf16* __restrict__ U2T,
          const float* __restrict__ bc, float* __restrict__ dvec)
{
    __shared__ __align__(16) bf16 TrT[256 * 24];    // transposed repack [256 f][16+8]
    __shared__ float dsum[4][16];

    const int tid = threadIdx.x;
    const int wave = tid >> 6, lane = tid & 63;
    const int q = lane >> 4, l16 = lane & 15;
    const int bm = blockIdx.x * 16;
    const int b = bm >> 10, n0 = bm & (NN - 1);

    // A: whole K in registers; lane l16 <-> row, q <-> k-octet
    const float* xr = x + (size_t)(bm + l16) * FD;
    bf16x8 af[8];
    #pragma unroll
    for (int ks = 0; ks < 8; ks++) {
        const float* p = xr + ks * 32 + q * 8;
        af[ks] = cvt8(*(const float4*)p, *(const float4*)(p + 4));
    }

    floatx4 acc[2][4] = {};   // [plane][nj]; plane0=ab, plane1=U2
    #pragma unroll
    for (int nj = 0; nj < 4; nj++) {
        const bf16* pA = WfA + (size_t)((wave * 4 + nj) * 8) * 512 + lane * 8;
        const bf16* pC = WfC + (size_t)((wave * 4 + nj) * 8) * 512 + lane * 8;
        #pragma unroll
        for (int ks = 0; ks < 8; ks++) {
            bf16x8 b0 = *(const bf16x8*)(pA + ks * 512);
            bf16x8 b1 = *(const bf16x8*)(pC + ks * 512);
            acc[0][nj] = __builtin_amdgcn_mfma_f32_16x16x32_bf16(af[ks], b0, acc[0][nj], 0, 0, 0);
            acc[1][nj] = __builtin_amdgcn_mfma_f32_16x16x32_bf16(af[ks], b1, acc[1][nj], 0, 0, 0);
        }
    }

    // diag: d[m] = sum_f x[m,f]*ab[m,f]; quarter-partials -> LDS -> single write
    float pq[4];
    #pragma unroll
    for (int i = 0; i < 4; i++) {
        const int m = bm + q * 4 + i;
        float p = 0.0f;
        #pragma unroll
        for (int nj = 0; nj < 4; nj++)
            p += x[(size_t)m * FD + wave * 64 + nj * 16 + l16] * acc[0][nj][i];
        #pragma unroll
        for (int off = 1; off < 16; off <<= 1) p += __shfl_xor(p, off);
        pq[i] = p;
    }
    if (l16 == 0) {
        #pragma unroll
        for (int i = 0; i < 4; i++) dsum[wave][q * 4 + i] = pq[i];
    }
    __syncthreads();
    if (tid < 16) dvec[bm + tid] = dsum[0][tid] + dsum[1][tid] + dsum[2][tid] + dsum[3][tid];

    float bcv[4];
    #pragma unroll
    for (int nj = 0; nj < 4; nj++) bcv[nj] = bc[wave * 64 + nj * 16 + l16];

    // transposed abT (pass 0), U2T (pass 1, +bc) via TrT
    #pragma unroll
    for (int pass = 0; pass < 2; pass++) {
        __syncthreads();
        #pragma unroll
        for (int nj = 0; nj < 4; nj++)
            #pragma unroll
            for (int i = 0; i < 4; i++) {
                float v = acc[pass][nj][i];
                if (pass == 1) v += bcv[nj];
                TrT[(wave * 64 + nj * 16 + l16) * 24 + q * 4 + i] = (bf16)v;
            }
        __syncthreads();
        bf16* dst = (pass ? U2T : abT) + (size_t)b * FD * NN;
        #pragma unroll
        for (int it = 0; it < 2; it++) {
            int c = tid + it * 256;
            int r = c >> 1, h = c & 1;
            *(bf16x8*)&dst[(size_t)r * NN + n0 + h * 8] = *(const bf16x8*)&TrT[r * 24 + h * 8];
        }
    }
}

// ---------------- K3: G[h][b][j][k] = sum_{n in half h} U2T[b][j][n]*abT[b][k][n] ----------------
// 64x64 tiles, split-K(2); grid 512 linear, XCD-swizzled: batch b -> XCD b&7.
__global__ __launch_bounds__(256, 2)
void m2_mfma(const bf16* __restrict__ U2T, const bf16* __restrict__ abT, float* __restrict__ G)
{
    const int lin = blockIdx.x;
    const int xcd = lin & 7, t = lin >> 3;          // assume consecutive ids round-robin XCDs
    const int b = (t >> 5) * 8 + xcd;               // 2 batches per XCD
    const int r = t & 31;
    const int h = r >> 4, bj = ((r >> 2) & 3) * 64, bk = (r & 3) * 64;

    const int tid = threadIdx.x;
    const int wave = tid >> 6, lane = tid & 63;
    const int q = lane >> 4, l16 = lane & 15;

    const bf16* ar = U2T + (size_t)b * FD * NN + (size_t)(bj + wave * 16 + l16) * NN + h * 512;
    const bf16* br = abT + (size_t)b * FD * NN + (size_t)(bk + l16) * NN + h * 512;

    floatx4 acc[4] = {};
    #pragma unroll 4
    for (int n0 = 0; n0 < 512; n0 += 32) {
        const int no = n0 + q * 8;
        bf16x8 af = *(const bf16x8*)&ar[no];
        #pragma unroll
        for (int nj = 0; nj < 4; nj++) {
            bf16x8 bq = *(const bf16x8*)&br[(size_t)nj * 16 * NN + no];
            acc[nj] = __builtin_amdgcn_mfma_f32_16x16x32_bf16(af, bq, acc[nj], 0, 0, 0);
        }
    }

    float* Gb = G + (size_t)h * GH + (size_t)b * FD * FD;
    #pragma unroll
    for (int i = 0; i < 4; i++) {
        const int j = bj + wave * 16 + q * 4 + i;
        #pragma unroll
        for (int nj = 0; nj < 4; nj++)
            Gb[(size_t)j * FD + bk + nj * 16 + l16] = acc[nj][i];
    }
}

// ---------------- K4: out = (x_bf @ G[b]^T - d*(x@WfC^T+bc))/N + x ----------------
// U2 recomputed inline from packed weights (L2-hot).  grid 1024 linear,
// XCD-swizzled: batch -> XCD b&7 (x strip + G[b] L2-resident per XCD).
__global__ __launch_bounds__(256, 4)
void final_mfma(const float* __restrict__ x, const float* __restrict__ G,
                const float* __restrict__ dvec, const bf16* __restrict__ WfC,
                const float* __restrict__ bc, float* __restrict__ out)
{
    const int lin = blockIdx.x;
    const int xcd = lin & 7, t = lin >> 3;
    const int bsub = t >> 6, rem = t & 63;
    const int bmi = rem >> 2, bn = rem & 3;
    const int b = bsub * 8 + xcd;
    const int m0 = (b * 16 + bmi) * 64;             // 64-row tile
    const int n0c = bn * 64;

    const int tid = threadIdx.x;
    const int wave = tid >> 6, lane = tid & 63;
    const int q = lane >> 4, l16 = lane & 15;

    const float* xr = x + (size_t)(m0 + wave * 16 + l16) * FD;
    const float* g0 = G + (size_t)b * FD * FD + (size_t)(n0c + l16) * FD;

    floatx4 acc[4] = {}, acc2[4] = {};
    #pragma unroll
    for (int ks = 0; ks < 8; ks++) {
        const int ko = ks * 32 + q * 8;
        bf16x8 af = cvt8(*(const float4*)&xr[ko], *(const float4*)&xr[ko + 4]);
        #pragma unroll
        for (int nj = 0; nj < 4; nj++) {
            const float* gp = g0 + (size_t)nj * 16 * FD + ko;
            float4 p0 = *(const float4*)gp,        p1 = *(const float4*)(gp + 4);
            float4 q0 = *(const float4*)(gp + GH), q1 = *(const float4*)(gp + GH + 4);
            float4 u = { p0.x + q0.x, p0.y + q0.y, p0.z + q0.z, p0.w + q0.w };
            float4 v = { p1.x + q1.x, p1.y + q1.y, p1.z + q1.z, p1.w + q1.w };
            bf16x8 bg = cvt8(u, v);
            acc[nj] = __builtin_amdgcn_mfma_f32_16x16x32_bf16(af, bg, acc[nj], 0, 0, 0);
            bf16x8 bu = *(const bf16x8*)(WfC + (size_t)((bn * 4 + nj) * 8 + ks) * 512 + lane * 8);
            acc2[nj] = __builtin_amdgcn_mfma_f32_16x16x32_bf16(af, bu, acc2[nj], 0, 0, 0);
        }
    }

    float bcv[4];
    #pragma unroll
    for (int nj = 0; nj < 4; nj++) bcv[nj] = bc[n0c + nj * 16 + l16];

    #pragma unroll
    for (int i = 0; i < 4; i++) {
        const int m = m0 + wave * 16 + q * 4 + i;
        const float d = dvec[m];
        #pragma unroll
        for (int nj = 0; nj < 4; nj++) {
            const int n = n0c + nj * 16 + l16;
            const float u2 = acc2[nj][i] + bcv[nj];
            const float v = (acc[nj][i] - d * u2) * (1.0f / 1024.0f);
            out[(size_t)m * FD + n] = v + x[(size_t)m * FD + n];
        }
    }
}

extern "C" void kernel_launch(void* const* d_in, const int* in_sizes, int n_in,
                              void* d_out, int out_size, void* d_ws, size_t ws_size,
                              hipStream_t stream)
{
    const float* x  = (const float*)d_in[0];
    const float* Wa = (const float*)d_in[1];
    const float* Wb = (const float*)d_in[2];
    const float* Wu = (const float*)d_in[3];
    const float* bu = (const float*)d_in[4];
    const float* Wr = (const float*)d_in[5];
    float* out = (float*)d_out;

    char* w = (char*)d_ws;
    bf16* WfC   = (bf16*)w;  w += (size_t)FD * FD * 2;
    bf16* WfA   = (bf16*)w;  w += (size_t)FD * FD * 2;
    float* bc   = (float*)w; w += (size_t)FD * 4;
    bf16* abT   = (bf16*)w;  w += (size_t)RR * FD * 2;
    bf16* U2T   = (bf16*)w;  w += (size_t)RR * FD * 2;
    float* G    = (float*)w; w += (size_t)2 * GH * 4;
    float* dvec = (float*)w; w += (size_t)RR * 4;

    dim3 blk(256);

    prep<<<dim3(513), blk, 0, stream>>>(Wa, Wb, Wu, bu, Wr, WfC, WfA, bc);

    proj<<<dim3(1024), blk, 0, stream>>>(x, WfA, WfC, abT, U2T, bc, dvec);

    m2_mfma<<<dim3(512), blk, 0, stream>>>(U2T, abT, G);

    final_mfma<<<dim3(1024), blk, 0, stream>>>(x, G, dvec, WfC, bc, out);
}

// Round 7
// 136.660 us; speedup vs baseline: 1.5075x; 1.5075x over previous
//
#include <hip/hip_runtime.h>

// x [B=16, N=1024, F=256] fp32.  Algebra (alpha folded away):
//   WfA = pack(Wa^T@Wb), WfC = pack(Wr@Wu), bc = Wr@bu    (prep)
//   ab = x@Wab^T, U2 = x@Wcb^T+bc (proj; outputs stored fragment-PACKED over n)
//   d[m] = x[m]·ab[m]
//   G[b][j][f] = sum_n U2T[b,j,n]*abT[b,f,n]   (m2; G stored fragment-PACKED over f)
//   out[m,j] = (x[m,:]·G[b][j,:] - d[m]*U2[m,j])/N + x[m,j]  (final; U2 refused inline)
// Round-7: EVERY MFMA operand pre-packed in fragment order -> every wave load
// is one contiguous 1KB burst (R5 proj's proven lever, now applied to m2+final).
// R6 lesson: byte count doesn't predict time; load structure does (74us final
// at 14MB fetch from dependent strided fp32 loads).

typedef __bf16 bf16;
typedef float floatx4 __attribute__((ext_vector_type(4)));
typedef bf16 bf16x8 __attribute__((ext_vector_type(8)));

constexpr int FD = 256;
constexpr int NB = 16;
constexpr int NN = 1024;
constexpr int RR = NB * NN;       // 16384

__device__ __forceinline__ bf16x8 cvt8(float4 a, float4 b) {
    bf16x8 o = { (bf16)a.x, (bf16)a.y, (bf16)a.z, (bf16)a.w,
                 (bf16)b.x, (bf16)b.y, (bf16)b.z, (bf16)b.w };
    return o;
}

// fragment-packed index for a [256 rows][256 k] B-operand:
// chunk (r16 = row>>4, k32 = k>>5) holds 512 elems; within chunk
// lane = ((k>>3)&3)*16 + (row&15), elem = k&7.   (lane*8 = contiguous burst)
__device__ __forceinline__ int pk(int r, int k) {
    return ((r >> 4) * 8 + (k >> 5)) * 512 + (((k >> 3) & 3) * 16 + (r & 15)) * 8 + (k & 7);
}

// ---------------- K1: prep ----------------
__global__ __launch_bounds__(256)
void prep(const float* __restrict__ Wa, const float* __restrict__ Wb,
          const float* __restrict__ Wu, const float* __restrict__ bu,
          const float* __restrict__ Wr,
          bf16* __restrict__ WfC, bf16* __restrict__ WfA, float* __restrict__ bc)
{
    const int blk = blockIdx.x, tid = threadIdx.x;
    if (blk < 256) {  // Wcb[j][f] = sum_g Wr[j][g]*Wu[g][f]; one j per block
        const int j = blk;
        float acc = 0.0f;
        for (int g = 0; g < FD; g += 4) {
            float4 wr = *(const float4*)&Wr[j * FD + g];
            acc += wr.x * Wu[g * FD + tid] + wr.y * Wu[(g + 1) * FD + tid]
                 + wr.z * Wu[(g + 2) * FD + tid] + wr.w * Wu[(g + 3) * FD + tid];
        }
        WfC[pk(j, tid)] = (bf16)acc;
    } else if (blk == 256) {  // bc[j] = Wr[j,:].bu
        float s = 0.0f;
        for (int g = 0; g < FD; g++) s += Wr[tid * FD + g] * bu[g];
        bc[tid] = s;
    } else {  // Wab[f][g] = sum_k Wa[k][f]*Wb[k][g]; one f per block
        const int f = blk - 257;
        float acc = 0.0f;
        for (int k = 0; k < FD; k += 4) {
            acc += Wa[k * FD + f] * Wb[k * FD + tid]
                 + Wa[(k + 1) * FD + f] * Wb[(k + 1) * FD + tid]
                 + Wa[(k + 2) * FD + f] * Wb[(k + 2) * FD + tid]
                 + Wa[(k + 3) * FD + f] * Wb[(k + 3) * FD + tid];
        }
        WfA[pk(f, tid)] = (bf16)acc;
    }
}

// ---------------- K2: proj (16-row strip x 256 cols; x once; packed B; packed outputs) ----------------
// 1024 blocks x 4 waves; wave w owns col-quarter [w*64, w*64+64).
// Packed output layout per batch: [256 f][1024 n]: chunk = (f>>4)*32 + (n>>5),
// within: lane = ((n>>3)&3)*16 + (f&15), elem n&7.
__global__ __launch_bounds__(256, 4)
void proj(const float* __restrict__ x,
          const bf16* __restrict__ WfA, const bf16* __restrict__ WfC,
          bf16* __restrict__ abTp, bf16* __restrict__ U2Tp,
          const float* __restrict__ bc, float* __restrict__ dvec)
{
    __shared__ __align__(16) bf16 TrT[256 * 24];    // [256 f][16 n + 8 pad]
    __shared__ float dsum[4][16];

    const int tid = threadIdx.x;
    const int wave = tid >> 6, lane = tid & 63;
    const int q = lane >> 4, l16 = lane & 15;
    const int bm = blockIdx.x * 16;
    const int b = bm >> 10, n0 = bm & (NN - 1);

    const float* xr = x + (size_t)(bm + l16) * FD;
    bf16x8 af[8];
    #pragma unroll
    for (int ks = 0; ks < 8; ks++) {
        const float* p = xr + ks * 32 + q * 8;
        af[ks] = cvt8(*(const float4*)p, *(const float4*)(p + 4));
    }

    floatx4 acc[2][4] = {};   // [plane][nj]; plane0=ab, plane1=U2
    #pragma unroll
    for (int nj = 0; nj < 4; nj++) {
        const bf16* pA = WfA + (size_t)((wave * 4 + nj) * 8) * 512 + lane * 8;
        const bf16* pC = WfC + (size_t)((wave * 4 + nj) * 8) * 512 + lane * 8;
        #pragma unroll
        for (int ks = 0; ks < 8; ks++) {
            bf16x8 b0 = *(const bf16x8*)(pA + ks * 512);
            bf16x8 b1 = *(const bf16x8*)(pC + ks * 512);
            acc[0][nj] = __builtin_amdgcn_mfma_f32_16x16x32_bf16(af[ks], b0, acc[0][nj], 0, 0, 0);
            acc[1][nj] = __builtin_amdgcn_mfma_f32_16x16x32_bf16(af[ks], b1, acc[1][nj], 0, 0, 0);
        }
    }

    // diag: d[m] = sum_f x[m,f]*ab[m,f]
    float pq[4];
    #pragma unroll
    for (int i = 0; i < 4; i++) {
        const int m = bm + q * 4 + i;
        float p = 0.0f;
        #pragma unroll
        for (int nj = 0; nj < 4; nj++)
            p += x[(size_t)m * FD + wave * 64 + nj * 16 + l16] * acc[0][nj][i];
        #pragma unroll
        for (int off = 1; off < 16; off <<= 1) p += __shfl_xor(p, off);
        pq[i] = p;
    }
    if (l16 == 0) {
        #pragma unroll
        for (int i = 0; i < 4; i++) dsum[wave][q * 4 + i] = pq[i];
    }
    __syncthreads();
    if (tid < 16) dvec[bm + tid] = dsum[0][tid] + dsum[1][tid] + dsum[2][tid] + dsum[3][tid];

    float bcv[4];
    #pragma unroll
    for (int nj = 0; nj < 4; nj++) bcv[nj] = bc[wave * 64 + nj * 16 + l16];

    const int o0 = (n0 >> 3) & 3;   // n-octet base within chunk (n0 mult of 16)
    #pragma unroll
    for (int pass = 0; pass < 2; pass++) {
        __syncthreads();
        #pragma unroll
        for (int nj = 0; nj < 4; nj++)
            #pragma unroll
            for (int i = 0; i < 4; i++) {
                float v = acc[pass][nj][i];
                if (pass == 1) v += bcv[nj];
                TrT[(wave * 64 + nj * 16 + l16) * 24 + q * 4 + i] = (bf16)v;
            }
        __syncthreads();
        bf16* dst = (pass ? U2Tp : abTp) + (size_t)b * FD * NN;
        #pragma unroll
        for (int it = 0; it < 2; it++) {
            int c = tid + it * 256;
            int r = c >> 1, h = c & 1;           // r = f, h = n-octet half
            bf16x8 v = *(const bf16x8*)&TrT[r * 24 + h * 8];
            int chunk = (r >> 4) * 32 + (n0 >> 5);
            *(bf16x8*)&dst[(size_t)chunk * 512 + ((o0 + h) * 16 + (r & 15)) * 8] = v;
        }
    }
}

// ---------------- K3: G[b][j][f] = sum_n U2T*abT (all operands packed; G packed) ----------------
// tile 64j x 32f; grid 512 linear; batch->XCD co-location (lin&7 = xcd).
__global__ __launch_bounds__(256, 2)
void m2_mfma(const bf16* __restrict__ U2Tp, const bf16* __restrict__ abTp, bf16* __restrict__ Gp)
{
    __shared__ __align__(16) bf16 Tr[64][40];
    const int lin = blockIdx.x;
    const int xcd = lin & 7, loc = lin >> 3;
    const int b = xcd + 8 * (loc >> 5);
    const int tile = loc & 31;
    const int bj = (tile >> 3) * 64, bk = (tile & 7) * 32;

    const int tid = threadIdx.x;
    const int wave = tid >> 6, lane = tid & 63;
    const int q = lane >> 4, l16 = lane & 15;

    const bf16* Ab = U2Tp + (size_t)b * FD * NN + lane * 8;
    const bf16* Bb = abTp + (size_t)b * FD * NN + lane * 8;
    const int ach = ((bj >> 4) + wave) * 32;        // A chunk row for this wave's 16 j's
    const int bch0 = (bk >> 4) * 32;                // B chunk rows (2 f-frags)
    const int bch1 = ((bk >> 4) + 1) * 32;

    floatx4 acc[2] = {};
    #pragma unroll 8
    for (int n5 = 0; n5 < 32; n5++) {               // n-chunk loop (32 n per step)
        bf16x8 af = *(const bf16x8*)&Ab[(size_t)(ach + n5) * 512];
        bf16x8 b0 = *(const bf16x8*)&Bb[(size_t)(bch0 + n5) * 512];
        bf16x8 b1 = *(const bf16x8*)&Bb[(size_t)(bch1 + n5) * 512];
        acc[0] = __builtin_amdgcn_mfma_f32_16x16x32_bf16(af, b0, acc[0], 0, 0, 0);
        acc[1] = __builtin_amdgcn_mfma_f32_16x16x32_bf16(af, b1, acc[1], 0, 0, 0);
    }

    // repack [64 j][32 f] -> packed-G burst stores
    #pragma unroll
    for (int i = 0; i < 4; i++)
        #pragma unroll
        for (int kj = 0; kj < 2; kj++)
            Tr[wave * 16 + q * 4 + i][kj * 16 + l16] = (bf16)acc[kj][i];
    __syncthreads();
    {
        const int jj = tid >> 2, oct = tid & 3;      // f = bk + oct*8
        bf16x8 v = *(const bf16x8*)&Tr[jj][oct * 8];
        const int chunk = ((bj + jj) >> 4) * 8 + (bk >> 5);
        *(bf16x8*)&Gp[(size_t)b * FD * FD + (size_t)chunk * 512
                      + (oct * 16 + ((bj + jj) & 15)) * 8] = v;
    }
}

// ---------------- K4: out = (x_bf @ G^T - d*(x@Wcb^T+bc))/N + x  (packed G + WfC) ----------------
__global__ __launch_bounds__(256, 4)
void final_mfma(const float* __restrict__ x, const bf16* __restrict__ Gp,
                const float* __restrict__ dvec, const bf16* __restrict__ WfC,
                const float* __restrict__ bc, float* __restrict__ out)
{
    const int tid = threadIdx.x;
    const int wave = tid >> 6, lane = tid & 63;
    const int q = lane >> 4, l16 = lane & 15;
    const int bn = blockIdx.x * 64, bm = blockIdx.y * 64;
    const int b = bm >> 10;

    const float* xr = x + (size_t)(bm + wave * 16 + l16) * FD;
    const bf16* Gb = Gp + (size_t)b * FD * FD + lane * 8;
    const bf16* Wc = WfC + lane * 8;
    const int cb = bn >> 4;

    floatx4 acc[4] = {}, acc2[4] = {};
    #pragma unroll
    for (int ks = 0; ks < 8; ks++) {
        const int ko = ks * 32 + q * 8;
        bf16x8 af = cvt8(*(const float4*)&xr[ko], *(const float4*)&xr[ko + 4]);
        #pragma unroll
        for (int nj = 0; nj < 4; nj++) {
            bf16x8 bg = *(const bf16x8*)&Gb[(size_t)((cb + nj) * 8 + ks) * 512];
            bf16x8 bu = *(const bf16x8*)&Wc[(size_t)((cb + nj) * 8 + ks) * 512];
            acc[nj]  = __builtin_amdgcn_mfma_f32_16x16x32_bf16(af, bg, acc[nj], 0, 0, 0);
            acc2[nj] = __builtin_amdgcn_mfma_f32_16x16x32_bf16(af, bu, acc2[nj], 0, 0, 0);
        }
    }

    float bcv[4];
    #pragma unroll
    for (int nj = 0; nj < 4; nj++) bcv[nj] = bc[bn + nj * 16 + l16];

    #pragma unroll
    for (int i = 0; i < 4; i++) {
        const int m = bm + wave * 16 + q * 4 + i;
        const float d = dvec[m];
        #pragma unroll
        for (int nj = 0; nj < 4; nj++) {
            const int n = bn + nj * 16 + l16;
            const float u2 = acc2[nj][i] + bcv[nj];
            const float v = (acc[nj][i] - d * u2) * (1.0f / 1024.0f);
            out[(size_t)m * FD + n] = v + x[(size_t)m * FD + n];
        }
    }
}

extern "C" void kernel_launch(void* const* d_in, const int* in_sizes, int n_in,
                              void* d_out, int out_size, void* d_ws, size_t ws_size,
                              hipStream_t stream)
{
    const float* x  = (const float*)d_in[0];
    const float* Wa = (const float*)d_in[1];
    const float* Wb = (const float*)d_in[2];
    const float* Wu = (const float*)d_in[3];
    const float* bu = (const float*)d_in[4];
    const float* Wr = (const float*)d_in[5];
    float* out = (float*)d_out;

    char* w = (char*)d_ws;
    bf16* WfC   = (bf16*)w;  w += (size_t)FD * FD * 2;
    bf16* WfA   = (bf16*)w;  w += (size_t)FD * FD * 2;
    float* bc   = (float*)w; w += (size_t)FD * 4;
    bf16* abTp  = (bf16*)w;  w += (size_t)RR * FD * 2;
    bf16* U2Tp  = (bf16*)w;  w += (size_t)RR * FD * 2;
    bf16* Gp    = (bf16*)w;  w += (size_t)NB * FD * FD * 2;
    float* dvec = (float*)w; w += (size_t)RR * 4;

    dim3 blk(256);

    prep<<<dim3(513), blk, 0, stream>>>(Wa, Wb, Wu, bu, Wr, WfC, WfA, bc);

    proj<<<dim3(1024), blk, 0, stream>>>(x, WfA, WfC, abTp, U2Tp, bc, dvec);

    m2_mfma<<<dim3(512), blk, 0, stream>>>(U2Tp, abTp, Gp);

    final_mfma<<<dim3(4, 256), blk, 0, stream>>>(x, Gp, dvec, WfC, bc, out);
}